// Round 6
// baseline (845.795 us; speedup 1.0000x reference)
//
#include <hip/hip_runtime.h>
#include <cstddef>

#define HH 16
#define TT 512
#define STG 16           // timesteps per stage (x-stage and h1-ring granularity)
#define NSTG (TT / STG)  // 32 stages
#define LOG2E 1.44269504088896340736f

typedef float v4f __attribute__((ext_vector_type(4)));

static __device__ __forceinline__ float fexp2(float x){ return __builtin_amdgcn_exp2f(x); }
static __device__ __forceinline__ float frcp (float x){ return __builtin_amdgcn_rcpf(x); }
static __device__ __forceinline__ float frsq (float x){ return __builtin_amdgcn_rsqf(x); }

// tanh(c) = 2/(1+exp(-2c)) - 1 ; saturates correctly (rcp(inf)=0)
static __device__ __forceinline__ float ftanh(float c){
    return frcp(1.0f + fexp2(c * (-2.0f*LOG2E))) * 2.0f - 1.0f;
}

// broadcast within each quad of lanes (VALU DPP)
template<int CTRL>
static __device__ __forceinline__ float qb(float v){
    return __builtin_bit_cast(float,
        __builtin_amdgcn_update_dpp(0, __builtin_bit_cast(int,v), CTRL, 0xF, 0xF, true));
}

// 16-MAC fp32 dot into 4 independent accumulator chains (compiler picks
// v_fmac_f32 / AGPR sourcing freely — no inline asm, see R5 post-mortem)
static __device__ __forceinline__ void fmac16(const v4f* a, const v4f* w,
                                              float& s0, float& s1, float& s2, float& s3){
    s0 = __builtin_fmaf(a[0].x, w[0].x, s0); s1 = __builtin_fmaf(a[0].y, w[0].y, s1);
    s2 = __builtin_fmaf(a[0].z, w[0].z, s2); s3 = __builtin_fmaf(a[0].w, w[0].w, s3);
    s0 = __builtin_fmaf(a[1].x, w[1].x, s0); s1 = __builtin_fmaf(a[1].y, w[1].y, s1);
    s2 = __builtin_fmaf(a[1].z, w[1].z, s2); s3 = __builtin_fmaf(a[1].w, w[1].w, s3);
    s0 = __builtin_fmaf(a[2].x, w[2].x, s0); s1 = __builtin_fmaf(a[2].y, w[2].y, s1);
    s2 = __builtin_fmaf(a[2].z, w[2].z, s2); s3 = __builtin_fmaf(a[2].w, w[2].w, s3);
    s0 = __builtin_fmaf(a[3].x, w[3].x, s0); s1 = __builtin_fmaf(a[3].y, w[3].y, s1);
    s2 = __builtin_fmaf(a[3].z, w[3].z, s2); s3 = __builtin_fmaf(a[3].w, w[3].w, s3);
}

static __device__ __forceinline__ void ld4(v4f* dst, const float* p){
    const v4f* q = (const v4f*)p;
    dst[0] = q[0]; dst[1] = q[1]; dst[2] = q[2]; dst[3] = q[3];
}

// Producer/consumer wave split: block = 128 thr = 2 waves = 1 batch element.
// wave0 computes layer-1 h1(t) into a double-buffered LDS ring (16 steps per
// stage); wave1 consumes stage s-1 computing layer-2. __syncthreads per stage.
// Each wave's serial chain is ONE layer; register need ~95/wave. All fp32
// (f16/bf16 fail: 512-step recurrence amplifies input noise ~1e3x — R4).
__global__ __launch_bounds__(128, 4) void lstm_fused_kernel(
    const float* __restrict__ x,
    const float* __restrict__ W_ih0, const float* __restrict__ W_hh0,
    const float* __restrict__ b_ih0, const float* __restrict__ b_hh0,
    const float* __restrict__ W_ih1, const float* __restrict__ W_hh1,
    const float* __restrict__ b_ih1, const float* __restrict__ b_hh1,
    const float* __restrict__ W_proj, const float* __restrict__ b_proj,
    const float* __restrict__ ln_g, const float* __restrict__ ln_b,
    float* __restrict__ out)
{
    const int lane = threadIdx.x & 63;
    const int wv   = threadIdx.x >> 6;   // 0 = layer-1 producer, 1 = layer-2 consumer
    const int b    = blockIdx.x;

    const int g   = lane & 3;        // 0=i 1=f 2=g 3=o
    const int k   = lane >> 2;       // hidden unit 0..15
    const int row = g * HH + k;      // row in [4H,H] weights (PyTorch order)

    // LDS: x ping[256] + x pong[256] + h1 ring A[256] + ring B[256] + h2[16]
    __shared__ float sh[1040];
    float* xb0 = sh;
    float* xb1 = sh + 256;
    float* r0  = sh + 512;
    float* r1  = sh + 768;
    float* h2w = sh + 1024;

    // activation constants: sigmoid for i,f,o ; tanh for g (=2*sig(2x)-1)
    const bool  isg    = (g == 2);
    const float sc_in  = isg ? (-2.0f * LOG2E) : (-LOG2E);
    const float sc_out = isg ? 2.0f : 1.0f;
    const float sh_out = isg ? 1.0f : 0.0f;

    // ---- this wave's layer weights, pre-scaled by sc_in (folds the gate
    //      pre-activation multiply into the dot) ----
    const float* Wih = wv ? W_ih1 : W_ih0;
    const float* Whh = wv ? W_hh1 : W_hh0;
    v4f wa[4], wb[4];
#pragma unroll
    for (int q = 0; q < 4; ++q) {
        wa[q] = ((const v4f*)(Wih + row * HH))[q] * sc_in;
        wb[q] = ((const v4f*)(Whh + row * HH))[q] * sc_in;
    }
    const float bias = (wv ? (b_ih1[row] + b_hh1[row])
                           : (b_ih0[row] + b_hh0[row])) * sc_in;

    const float* xg = x + (size_t)b * TT * HH;

    float c = 0.0f;                  // c1 (wave0) or c2 (wave1)
    v4f st[4];                        // h1(t-1) (wave0) or h2(t-1) (wave1)
#pragma unroll
    for (int q = 0; q < 4; ++q) st[q] = (v4f)(0.f);

    v4f xa[4];                        // wave0: x(t) broadcast
    v4f xs = (v4f)(0.f);              // wave0: global x prefetch
    v4f h1d[2][4];                    // wave1: h1 input double-buffer

    if (wv == 0) {
        // prologue: stage 0 into xb0, prefetch stage 1, broadcast x(0)
        xs = *(const v4f*)(xg + lane * 4);
        *(v4f*)(xb0 + lane * 4) = xs;
        asm volatile("" ::: "memory");
        xs = *(const v4f*)(xg + 256 + lane * 4);
        ld4(xa, xb0);
    }

    for (int s = 0; s <= NSTG; ++s) {
        if (wv == 0 && s < NSTG) {
            // ================= layer-1 producer, stage s =================
            float* cur  = (s & 1) ? xb1 : xb0;
            float* nxt  = (s & 1) ? xb0 : xb1;
            float* ring = (s & 1) ? r1  : r0;

            *(v4f*)(nxt + lane * 4) = xs;          // x stage s+1 -> LDS
            const int sp = (s + 2 < NSTG) ? (s + 2) : (NSTG - 1);
            xs = *(const v4f*)(xg + (size_t)sp * 256 + lane * 4);

#pragma unroll
            for (int ti = 0; ti < STG; ++ti) {
                float s0 = bias, s1 = 0.f, s2 = 0.f, s3 = 0.f;
                fmac16(xa, wa, s0, s1, s2, s3);    // x(t) . Wih0 (pre-scaled)
                fmac16(st, wb, s0, s1, s2, s3);    // h1(t-1) . Whh0
                float a1 = (s0 + s1) + (s2 + s3);  // already *sc_in
                float act = frcp(1.0f + fexp2(a1)) * sc_out - sh_out;
                float iv = qb<0x00>(act), fv = qb<0x55>(act);
                float gv = qb<0xAA>(act), ov = qb<0xFF>(act);
                c = __builtin_fmaf(fv, c, iv * gv);
                float hn = ov * ftanh(c);
                ring[ti * HH + k] = hn;            // publish h1(t)
                asm volatile("" ::: "memory");
                ld4(st, ring + ti * HH);           // self-broadcast h1(t)
                // x(t+1) broadcast; ti=15 crosses into next stage's buffer
                ld4(xa, (ti < 15) ? (cur + (ti + 1) * HH) : nxt);
            }
        }
        if (wv == 1 && s >= 1) {
            // ================= layer-2 consumer, stage s-1 =================
            float* rprev = (s & 1) ? r0 : r1;      // ring written at stage s-1
            ld4(h1d[0], rprev);                    // h1 input, slot 0
#pragma unroll
            for (int ti = 0; ti < STG; ++ti) {
                const v4f* h1c = h1d[ti & 1];
                float q0 = bias, q1 = 0.f, q2 = 0.f, q3 = 0.f;
                fmac16(h1c, wa, q0, q1, q2, q3);   // h1(t) . Wih1
                if (ti < 15) ld4(h1d[(ti + 1) & 1], rprev + (ti + 1) * HH);
                fmac16(st, wb, q0, q1, q2, q3);    // h2(t-1) . Whh1
                float a2 = (q0 + q1) + (q2 + q3);
                float act = frcp(1.0f + fexp2(a2)) * sc_out - sh_out;
                float iv = qb<0x00>(act), fv = qb<0x55>(act);
                float gv = qb<0xAA>(act), ov = qb<0xFF>(act);
                c = __builtin_fmaf(fv, c, iv * gv);
                float hn = ov * ftanh(c);
                h2w[k] = hn;                       // publish h2(t)
                asm volatile("" ::: "memory");
                ld4(st, h2w);                      // self-broadcast h2(t)
            }
        }
        __syncthreads();                           // stage handoff (both waves)
    }

    if (wv == 0) return;

    // ---- epilogue (wave1): z = h2(T-1) @ W_proj^T + b_proj ; LN ; tanh ----
    const int u = lane & 15;   // output unit (replicated x4 across the wave)
    v4f wp[4];
#pragma unroll
    for (int q = 0; q < 4; ++q) wp[q] = ((const v4f*)(W_proj + u * HH))[q];
    float s0 = b_proj[u], s1 = 0.f, s2 = 0.f, s3 = 0.f;
    fmac16(st, wp, s0, s1, s2, s3);
    float z = (s0 + s1) + (s2 + s3);

    // stats across the 16-lane group (xor masks 1,2,4,8 stay in-group)
    float sacc = z;
    sacc += __shfl_xor(sacc, 1); sacc += __shfl_xor(sacc, 2);
    sacc += __shfl_xor(sacc, 4); sacc += __shfl_xor(sacc, 8);
    const float mu = sacc * (1.0f / 16.0f);

    const float d = z - mu;
    float qq = d * d;
    qq += __shfl_xor(qq, 1); qq += __shfl_xor(qq, 2);
    qq += __shfl_xor(qq, 4); qq += __shfl_xor(qq, 8);
    const float var = qq * (1.0f / 16.0f);

    const float rs  = frsq(var + 1e-5f);
    const float y   = d * rs * ln_g[u] + ln_b[u];
    const float res = ftanh(y);

    if (lane < 16) out[(size_t)b * HH + lane] = res;
}

extern "C" void kernel_launch(void* const* d_in, const int* in_sizes, int n_in,
                              void* d_out, int out_size, void* d_ws, size_t ws_size,
                              hipStream_t stream) {
    const float* x      = (const float*)d_in[0];
    const float* W_ih0  = (const float*)d_in[1];
    const float* W_hh0  = (const float*)d_in[2];
    const float* b_ih0  = (const float*)d_in[3];
    const float* b_hh0  = (const float*)d_in[4];
    const float* W_ih1  = (const float*)d_in[5];
    const float* W_hh1  = (const float*)d_in[6];
    const float* b_ih1  = (const float*)d_in[7];
    const float* b_hh1  = (const float*)d_in[8];
    const float* W_proj = (const float*)d_in[9];
    const float* b_proj = (const float*)d_in[10];
    const float* ln_g   = (const float*)d_in[11];
    const float* ln_b   = (const float*)d_in[12];
    float* out = (float*)d_out;

    const int B = in_sizes[0] / (TT * HH);   // 4096
    dim3 grid(B), block(128);                // 2 waves (L1+L2) per batch element
    hipLaunchKernelGGL(lstm_fused_kernel, grid, block, 0, stream,
                       x, W_ih0, W_hh0, b_ih0, b_hh0,
                       W_ih1, W_hh1, b_ih1, b_hh1,
                       W_proj, b_proj, ln_g, ln_b, out);
}

// Round 7
// 663.694 us; speedup vs baseline: 1.2744x; 1.2744x over previous
//
#include <hip/hip_runtime.h>
#include <cstddef>

#define HH 16
#define TT 512
#define STG 16           // timesteps per stage (x-stage and h1-ring granularity)
#define NSTG (TT / STG)  // 32 stages
#define LOG2E 1.44269504088896340736f

typedef float v4f __attribute__((ext_vector_type(4)));

static __device__ __forceinline__ float fexp2(float x){ return __builtin_amdgcn_exp2f(x); }
static __device__ __forceinline__ float frcp (float x){ return __builtin_amdgcn_rcpf(x); }
static __device__ __forceinline__ float frsq (float x){ return __builtin_amdgcn_rsqf(x); }

// tanh(c) = 2/(1+exp(-2c)) - 1 ; saturates correctly (rcp(inf)=0)
static __device__ __forceinline__ float ftanh(float c){
    return frcp(1.0f + fexp2(c * (-2.0f*LOG2E))) * 2.0f - 1.0f;
}

// broadcast within each quad of lanes (VALU DPP)
template<int CTRL>
static __device__ __forceinline__ float qb(float v){
    return __builtin_bit_cast(float,
        __builtin_amdgcn_update_dpp(0, __builtin_bit_cast(int,v), CTRL, 0xF, 0xF, true));
}

// 16-MAC fp32 dot into 4 independent accumulator chains (no inline asm:
// the compiler must stay free to source weights from AGPRs — R5 lesson)
static __device__ __forceinline__ void fmac16(const v4f* a, const v4f* w,
                                              float& s0, float& s1, float& s2, float& s3){
    s0 = __builtin_fmaf(a[0].x, w[0].x, s0); s1 = __builtin_fmaf(a[0].y, w[0].y, s1);
    s2 = __builtin_fmaf(a[0].z, w[0].z, s2); s3 = __builtin_fmaf(a[0].w, w[0].w, s3);
    s0 = __builtin_fmaf(a[1].x, w[1].x, s0); s1 = __builtin_fmaf(a[1].y, w[1].y, s1);
    s2 = __builtin_fmaf(a[1].z, w[1].z, s2); s3 = __builtin_fmaf(a[1].w, w[1].w, s3);
    s0 = __builtin_fmaf(a[2].x, w[2].x, s0); s1 = __builtin_fmaf(a[2].y, w[2].y, s1);
    s2 = __builtin_fmaf(a[2].z, w[2].z, s2); s3 = __builtin_fmaf(a[2].w, w[2].w, s3);
    s0 = __builtin_fmaf(a[3].x, w[3].x, s0); s1 = __builtin_fmaf(a[3].y, w[3].y, s1);
    s2 = __builtin_fmaf(a[3].z, w[3].z, s2); s3 = __builtin_fmaf(a[3].w, w[3].w, s3);
}

static __device__ __forceinline__ void ld4(v4f* dst, const float* p){
    const v4f* q = (const v4f*)p;
    dst[0] = q[0]; dst[1] = q[1]; dst[2] = q[2]; dst[3] = q[3];
}

// Producer/consumer wave split with a SINGLE shared inner body (R6 spilled
// because the two divergent bodies' union blew the register budget).
// Block = 128 thr = 2 waves = 1 batch element. wave0 = layer 1 (input: staged
// x, output: h1 ring), wave1 = layer 2 one stage behind (input: h1 ring,
// output: private self-broadcast scratch). Only pointers differ per wave.
// All fp32 (512-step recurrence amplifies input noise ~1e3x; f16 fails — R4).
__global__ __launch_bounds__(128, 5) void lstm_fused_kernel(
    const float* __restrict__ x,
    const float* __restrict__ W_ih0, const float* __restrict__ W_hh0,
    const float* __restrict__ b_ih0, const float* __restrict__ b_hh0,
    const float* __restrict__ W_ih1, const float* __restrict__ W_hh1,
    const float* __restrict__ b_ih1, const float* __restrict__ b_hh1,
    const float* __restrict__ W_proj, const float* __restrict__ b_proj,
    const float* __restrict__ ln_g, const float* __restrict__ ln_b,
    float* __restrict__ out)
{
    const int lane = threadIdx.x & 63;
    const int wv   = threadIdx.x >> 6;   // 0 = layer-1 producer, 1 = layer-2 consumer
    const int b    = blockIdx.x;

    const int g   = lane & 3;        // 0=i 1=f 2=g 3=o
    const int k   = lane >> 2;       // hidden unit 0..15
    const int row = g * HH + k;      // row in [4H,H] weights (PyTorch order)

    // LDS: x ping/pong [2x256] + h1 ring [2x256] + wave1 scratch [256]
    __shared__ __align__(16) float sh[1280];
    float* xbuf0 = sh;
    float* xbuf1 = sh + 256;
    float* ring0 = sh + 512;
    float* ring1 = sh + 768;
    float* h2s   = sh + 1024;

    // activation constants: sigmoid for i,f,o ; tanh for g (=2*sig(2x)-1)
    const bool  isg    = (g == 2);
    const float sc_in  = isg ? (-2.0f * LOG2E) : (-LOG2E);
    const float sc_out = isg ? 2.0f : 1.0f;
    const float sh_out = isg ? 1.0f : 0.0f;

    // this wave's layer weights, pre-scaled by sc_in (folds gate scaling)
    const float* Wih = wv ? W_ih1 : W_ih0;
    const float* Whh = wv ? W_hh1 : W_hh0;
    v4f wa[4], wb[4];
#pragma unroll
    for (int q = 0; q < 4; ++q) {
        wa[q] = ((const v4f*)(Wih + row * HH))[q] * sc_in;
        wb[q] = ((const v4f*)(Whh + row * HH))[q] * sc_in;
    }
    const float bias = (wv ? (b_ih1[row] + b_hh1[row])
                           : (b_ih0[row] + b_hh0[row])) * sc_in;

    const float* xg = x + (size_t)b * TT * HH;

    float c = 0.0f;                  // c1 (wave0) / c2 (wave1)
    v4f st[4];                        // h1(t-1) (wave0) / h2(t-1) (wave1)
#pragma unroll
    for (int q = 0; q < 4; ++q) st[q] = (v4f)(0.f);

    // prologue: wave0 stages x stage 0, prefetches stage 1 into regs
    v4f xs = (v4f)(0.f);
    if (wv == 0) {
        xs = *(const v4f*)(xg + lane * 4);
        *(v4f*)(xbuf0 + lane * 4) = xs;
        asm volatile("" ::: "memory");
        xs = *(const v4f*)(xg + 256 + lane * 4);
    }

    for (int s = 0; s <= NSTG; ++s) {
        // wave0: store prefetched x stage s+1, prefetch stage s+2 (clamped)
        if (wv == 0 && s + 1 < NSTG) {
            float* nxt = (s & 1) ? xbuf0 : xbuf1;
            *(v4f*)(nxt + lane * 4) = xs;
            asm volatile("" ::: "memory");
            const int sp = (s + 2 < NSTG) ? (s + 2) : (NSTG - 1);
            xs = *(const v4f*)(xg + (size_t)sp * 256 + lane * 4);
        }

        // per-wave data pointers (wave-uniform selects, shared body below)
        const float* inb;
        float*       outb;
        if (wv == 0) {
            inb  = (s & 1) ? xbuf1 : xbuf0;    // x stage s
            outb = (s & 1) ? ring1 : ring0;    // h1 ring for stage s
        } else {
            inb  = (s & 1) ? ring0 : ring1;    // h1 ring written at stage s-1
            outb = h2s;                        // private self-broadcast scratch
        }
        const bool active = wv ? (s >= 1) : (s < NSTG);

        if (active) {
#pragma unroll
            for (int ti = 0; ti < STG; ++ti) {
                v4f in[4];
                ld4(in, inb + ti * HH);              // input vector for step t
                float s0 = bias, s1 = 0.f, s2 = 0.f, s3 = 0.f;
                fmac16(in, wa, s0, s1, s2, s3);      // in . Wih (pre-scaled)
                fmac16(st, wb, s0, s1, s2, s3);      // h(t-1) . Whh
                float a   = (s0 + s1) + (s2 + s3);   // already * sc_in
                float act = __builtin_fmaf(frcp(1.0f + fexp2(a)), sc_out, -sh_out);
                float iv = qb<0x00>(act), fv = qb<0x55>(act);
                float gv = qb<0xAA>(act), ov = qb<0xFF>(act);
                c = __builtin_fmaf(fv, c, iv * gv);
                float hn = ov * ftanh(c);
                outb[ti * HH + k] = hn;              // publish h(t)
                asm volatile("" ::: "memory");
                ld4(st, outb + ti * HH);             // self-broadcast h(t)
            }
        }
        __syncthreads();                             // ring handoff
    }

    if (wv == 0) return;

    // ---- epilogue (wave1): z = h2(T-1) @ W_proj^T + b_proj ; LN ; tanh ----
    const int u = lane & 15;   // output unit (replicated x4 across the wave)
    v4f wp[4];
#pragma unroll
    for (int q = 0; q < 4; ++q) wp[q] = ((const v4f*)(W_proj + u * HH))[q];
    float s0 = b_proj[u], s1 = 0.f, s2 = 0.f, s3 = 0.f;
    fmac16(st, wp, s0, s1, s2, s3);
    float z = (s0 + s1) + (s2 + s3);

    // stats across the 16-lane group (xor masks 1,2,4,8 stay in-group)
    float sacc = z;
    sacc += __shfl_xor(sacc, 1); sacc += __shfl_xor(sacc, 2);
    sacc += __shfl_xor(sacc, 4); sacc += __shfl_xor(sacc, 8);
    const float mu = sacc * (1.0f / 16.0f);

    const float d = z - mu;
    float qq = d * d;
    qq += __shfl_xor(qq, 1); qq += __shfl_xor(qq, 2);
    qq += __shfl_xor(qq, 4); qq += __shfl_xor(qq, 8);
    const float var = qq * (1.0f / 16.0f);

    const float rs  = frsq(var + 1e-5f);
    const float y   = d * rs * ln_g[u] + ln_b[u];
    const float res = ftanh(y);

    if (lane < 16) out[(size_t)b * HH + lane] = res;
}

extern "C" void kernel_launch(void* const* d_in, const int* in_sizes, int n_in,
                              void* d_out, int out_size, void* d_ws, size_t ws_size,
                              hipStream_t stream) {
    const float* x      = (const float*)d_in[0];
    const float* W_ih0  = (const float*)d_in[1];
    const float* W_hh0  = (const float*)d_in[2];
    const float* b_ih0  = (const float*)d_in[3];
    const float* b_hh0  = (const float*)d_in[4];
    const float* W_ih1  = (const float*)d_in[5];
    const float* W_hh1  = (const float*)d_in[6];
    const float* b_ih1  = (const float*)d_in[7];
    const float* b_hh1  = (const float*)d_in[8];
    const float* W_proj = (const float*)d_in[9];
    const float* b_proj = (const float*)d_in[10];
    const float* ln_g   = (const float*)d_in[11];
    const float* ln_b   = (const float*)d_in[12];
    float* out = (float*)d_out;

    const int B = in_sizes[0] / (TT * HH);   // 4096
    dim3 grid(B), block(128);                // 2 waves (L1 | L2) per batch element
    hipLaunchKernelGGL(lstm_fused_kernel, grid, block, 0, stream,
                       x, W_ih0, W_hh0, b_ih0, b_hh0,
                       W_ih1, W_hh1, b_ih1, b_hh1,
                       W_proj, b_proj, ln_g, ln_b, out);
}